// Round 3
// baseline (36390.640 us; speedup 1.0000x reference)
//
#include <hip/hip_runtime.h>
#include <hip/hip_bf16.h>

#define N_PTS 16384
#define M_CTR 4096
#define NIN   64
#define NOUT  128
#define DIM   67
#define KNBR  64
#define R2    0.25f
#define BNI   0.9999950000374997f   // 1/sqrt(1+1e-5)

// ws layout (bytes): sel int[4096] @0 ; nvalid int[4096] @16384 ; nbr int[4096*64] @32768 (ends 1081344)

__device__ inline unsigned long long shfl_xor_u64(unsigned long long v, int m){
  int lo = __shfl_xor((int)(unsigned)v, m, 64);
  int hi = __shfl_xor((int)(unsigned)(v >> 32), m, 64);
  return ((unsigned long long)(unsigned)hi << 32) | (unsigned)lo;
}

// ---------------- FPS: single block, exact-rounding to match numpy ----------
#define FPS_T 512
#define FPS_K (N_PTS / FPS_T)   // 32 points per thread, strided ownership

__global__ __launch_bounds__(FPS_T) void fps_kernel(const float* __restrict__ pos,
                                                    int* __restrict__ sel) {
  __shared__ float c3[3];
  __shared__ unsigned long long wkey[2][8];
  const int t = threadIdx.x;
  float px[FPS_K], py[FPS_K], pz[FPS_K], dmin[FPS_K];
#pragma unroll
  for (int k = 0; k < FPS_K; k++) {
    int g = t + FPS_T * k;
    px[k] = pos[3*g+0]; py[k] = pos[3*g+1]; pz[k] = pos[3*g+2];
    dmin[k] = 3.4028235e38f;
  }
  if (t == 0) { c3[0] = pos[0]; c3[1] = pos[1]; c3[2] = pos[2]; sel[0] = 0; }
  __syncthreads();
  for (int s = 1; s < M_CTR; s++) {
    const float X = c3[0], Y = c3[1], Z = c3[2];
    float v = 0.0f, bx = px[0], by = py[0], bz = pz[0];
    int iL = 0;
#pragma unroll
    for (int k = 0; k < FPS_K; k++) {
      float dx = __fsub_rn(px[k], X);
      float dy = __fsub_rn(py[k], Y);
      float dz = __fsub_rn(pz[k], Z);
      float q  = __fadd_rn(__fadd_rn(__fmul_rn(dx,dx), __fmul_rn(dy,dy)), __fmul_rn(dz,dz));
      float d  = fminf(dmin[k], q);
      dmin[k]  = d;
      bool c = d > v;           // strict > keeps earliest index on ties
      v  = c ? d : v;  iL = c ? k : iL;
      bx = c ? px[k] : bx; by = c ? py[k] : by; bz = c ? pz[k] : bz;
    }
    unsigned g = (unsigned)t + ((unsigned)iL * FPS_T);
    unsigned long long mykey =
        (((unsigned long long)__float_as_uint(v)) << 32) |
        (unsigned long long)(0xFFFFFFFFu - g);   // larger val wins; ties -> smaller idx
    unsigned long long key = mykey;
#pragma unroll
    for (int m = 32; m >= 1; m >>= 1) {
      unsigned long long o = shfl_xor_u64(key, m);
      key = (o > key) ? o : key;
    }
    if ((t & 63) == 0) wkey[s & 1][t >> 6] = key;
    __syncthreads();
    unsigned long long kb = wkey[s & 1][0];
#pragma unroll
    for (int w = 1; w < 8; w++) { unsigned long long o = wkey[s & 1][w]; kb = (o > kb) ? o : kb; }
    if (mykey == kb) {   // unique winner thread: publish coords + index
      c3[0] = bx; c3[1] = by; c3[2] = bz;
      sel[s] = (int)(0xFFFFFFFFu - (unsigned)kb);
    }
    __syncthreads();
  }
}

// ---------------- ball query: one THREAD per centroid, top-64 insertion -----
__global__ __launch_bounds__(256) void ballq_kernel(const float* __restrict__ pos,
                                                    const int* __restrict__ sel,
                                                    int* __restrict__ nbr,
                                                    int* __restrict__ nvalid) {
  int i = blockIdx.x * 256 + threadIdx.x;
  if (i >= M_CTR) return;
  int ci = sel[i];
  ci = min(max(ci, 0), N_PTS - 1);
  const float X = pos[3*ci], Y = pos[3*ci+1], Z = pos[3*ci+2];
  unsigned long long best[KNBR];
#pragma unroll
  for (int k = 0; k < KNBR; k++) best[k] = ~0ull;
  for (int g = 0; g < N_PTS; g++) {
    float dx = __fsub_rn(pos[3*g+0], X);
    float dy = __fsub_rn(pos[3*g+1], Y);
    float dz = __fsub_rn(pos[3*g+2], Z);
    float q  = __fadd_rn(__fadd_rn(__fmul_rn(dx,dx), __fmul_rn(dy,dy)), __fmul_rn(dz,dz));
    if (q <= R2) {
      unsigned long long key = (((unsigned long long)__float_as_uint(q)) << 32) | (unsigned)g;
      if (key < best[KNBR-1]) {          // smallest (d2, idx) keys kept, stable like top_k
        int p = KNBR - 1;
        while (p > 0 && best[p-1] > key) { best[p] = best[p-1]; p--; }
        best[p] = key;
      }
    }
  }
  int cnt = 0;
  for (int k = 0; k < KNBR; k++) {
    if (best[k] != ~0ull) { nbr[i*KNBR+k] = (int)(unsigned)(best[k] & 0xFFFFFFFFull); cnt++; }
    else                  { nbr[i*KNBR+k] = 0; }
  }
  nvalid[i] = cnt;
}

// ---------------- per-centroid MLP + max aggregate (simple) -----------------
__global__ __launch_bounds__(128) void mlp_kernel(
    const float* __restrict__ x, const float* __restrict__ pos,
    const float* __restrict__ w1, const float* __restrict__ b1,
    const float* __restrict__ g1, const float* __restrict__ be1,
    const float* __restrict__ w2, const float* __restrict__ b2,
    const float* __restrict__ g2, const float* __restrict__ be2,
    const int* __restrict__ sel, const int* __restrict__ nbr,
    const int* __restrict__ nvalid, float* __restrict__ out) {
  __shared__ float xs[NIN];
  __shared__ float h1[DIM];
  __shared__ float rel[3];
  const int i = blockIdx.x, t = threadIdx.x;
  int ci = sel[i]; ci = min(max(ci, 0), N_PTS - 1);
  const float cx = pos[3*ci], cy = pos[3*ci+1], cz = pos[3*ci+2];
  int nv = nvalid[i]; nv = min(max(nv, 0), KNBR);
  float omax = -3.4028235e38f;
  for (int j = 0; j < nv; j++) {
    int nj = nbr[i*KNBR + j]; nj = min(max(nj, 0), N_PTS - 1);
    if (t < NIN) xs[t] = x[nj*NIN + t];
    if (t == 0) { rel[0] = pos[3*nj]-cx; rel[1] = pos[3*nj+1]-cy; rel[2] = pos[3*nj+2]-cz; }
    __syncthreads();
    if (t < DIM) {
      float z = b1[t];
      for (int r = 0; r < NIN; r++) z = fmaf(xs[r], w1[r*DIM + t], z);
      z = fmaf(rel[0], w1[64*DIM + t], z);
      z = fmaf(rel[1], w1[65*DIM + t], z);
      z = fmaf(rel[2], w1[66*DIM + t], z);
      z = fmaxf(z, 0.0f);
      h1[t] = g1[t] * (z * BNI) + be1[t];
    }
    __syncthreads();
    float acc = b2[t];
    for (int c = 0; c < DIM; c++) acc = fmaf(h1[c], w2[c*NOUT + t], acc);
    float h2v = g2[t] * (fmaxf(acc, 0.0f) * BNI) + be2[t];
    omax = fmaxf(omax, h2v);
    __syncthreads();
  }
  if (nv == 0) omax = 0.0f;   // cannot happen in a correct run; keeps values sane
  out[i*NOUT + t] = omax;
}

// ---------------- finalize: pos_s, batch, idx (float32 out) -----------------
__global__ void fin_kernel(const float* __restrict__ pos, const int* __restrict__ batch,
                           const int* __restrict__ sel, float* __restrict__ out) {
  int i = blockIdx.x * blockDim.x + threadIdx.x;
  if (i < M_CTR) {
    int s = sel[i];
    int sc = min(max(s, 0), N_PTS - 1);          // clamp gathers; write raw s as idx
    out[M_CTR*NOUT + 3*i + 0] = pos[3*sc+0];
    out[M_CTR*NOUT + 3*i + 1] = pos[3*sc+1];
    out[M_CTR*NOUT + 3*i + 2] = pos[3*sc+2];
    out[M_CTR*NOUT + 3*M_CTR + i] = (float)batch[sc];
    out[M_CTR*NOUT + 4*M_CTR + i] = (float)s;
  }
}

extern "C" void kernel_launch(void* const* d_in, const int* in_sizes, int n_in,
                              void* d_out, int out_size, void* d_ws, size_t ws_size,
                              hipStream_t stream) {
  const float* x   = (const float*)d_in[0];
  const float* pos = (const float*)d_in[1];
  const int*  batch= (const int*)d_in[2];
  const float* w1  = (const float*)d_in[3];
  const float* b1  = (const float*)d_in[4];
  const float* g1  = (const float*)d_in[5];
  const float* be1 = (const float*)d_in[6];
  const float* w2  = (const float*)d_in[7];
  const float* b2  = (const float*)d_in[8];
  const float* g2  = (const float*)d_in[9];
  const float* be2 = (const float*)d_in[10];
  float* out = (float*)d_out;

  char* ws   = (char*)d_ws;
  int*  sel  = (int*)(ws);
  int*  nvld = (int*)(ws + 16384);
  int*  nbr  = (int*)(ws + 32768);

  hipLaunchKernelGGL(fps_kernel,   dim3(1),       dim3(FPS_T), 0, stream, pos, sel);
  hipLaunchKernelGGL(ballq_kernel, dim3(16),      dim3(256),   0, stream, pos, sel, nbr, nvld);
  hipLaunchKernelGGL(mlp_kernel,   dim3(M_CTR),   dim3(128),   0, stream,
                     x, pos, w1, b1, g1, be1, w2, b2, g2, be2, sel, nbr, nvld, out);
  hipLaunchKernelGGL(fin_kernel,   dim3(16),      dim3(256),   0, stream, pos, batch, sel, out);
}

// Round 4
// 7919.151 us; speedup vs baseline: 4.5953x; 4.5953x over previous
//
#include <hip/hip_runtime.h>
#include <hip/hip_bf16.h>

#define N_PTS 16384
#define M_CTR 4096
#define NIN   64
#define NOUT  128
#define DIM   67
#define KNBR  64
#define R2    0.25f
#define BNI   0.9999950000374997f   // 1/sqrt(1+1e-5)

// ws layout (bytes): sel int[4096] @0 ; nvalid int[4096] @16384 ; nbr int[4096*64] @32768 ;
//                    U float[16384*67] @1081344 (ends 5472256) — used only if ws_size permits

__device__ inline unsigned long long shfl_xor_u64(unsigned long long v, int m){
  int lo = __shfl_xor((int)(unsigned)v, m, 64);
  int hi = __shfl_xor((int)(unsigned)(v >> 32), m, 64);
  return ((unsigned long long)(unsigned)hi << 32) | (unsigned)lo;
}

// ---------------- FPS: single block, exact-rounding to match numpy ----------
#define FPS_T 512
#define FPS_K (N_PTS / FPS_T)   // 32 points per thread, strided ownership

__global__ __launch_bounds__(FPS_T) void fps_kernel(const float* __restrict__ pos,
                                                    int* __restrict__ sel) {
  __shared__ float c3[3];
  __shared__ unsigned long long wkey[2][8];
  const int t = threadIdx.x;
  float px[FPS_K], py[FPS_K], pz[FPS_K], dmin[FPS_K];
#pragma unroll
  for (int k = 0; k < FPS_K; k++) {
    int g = t + FPS_T * k;
    px[k] = pos[3*g+0]; py[k] = pos[3*g+1]; pz[k] = pos[3*g+2];
    dmin[k] = 3.4028235e38f;
  }
  if (t == 0) { c3[0] = pos[0]; c3[1] = pos[1]; c3[2] = pos[2]; sel[0] = 0; }
  __syncthreads();
  for (int s = 1; s < M_CTR; s++) {
    const float X = c3[0], Y = c3[1], Z = c3[2];
    float v = 0.0f, bx = px[0], by = py[0], bz = pz[0];
    int iL = 0;
#pragma unroll
    for (int k = 0; k < FPS_K; k++) {
      float dx = __fsub_rn(px[k], X);
      float dy = __fsub_rn(py[k], Y);
      float dz = __fsub_rn(pz[k], Z);
      float q  = __fadd_rn(__fadd_rn(__fmul_rn(dx,dx), __fmul_rn(dy,dy)), __fmul_rn(dz,dz));
      float d  = fminf(dmin[k], q);
      dmin[k]  = d;
      bool c = d > v;           // strict > keeps earliest index on ties
      v  = c ? d : v;  iL = c ? k : iL;
      bx = c ? px[k] : bx; by = c ? py[k] : by; bz = c ? pz[k] : bz;
    }
    unsigned g = (unsigned)t + ((unsigned)iL * FPS_T);
    unsigned long long mykey =
        (((unsigned long long)__float_as_uint(v)) << 32) |
        (unsigned long long)(0xFFFFFFFFu - g);   // larger val wins; ties -> smaller idx
    unsigned long long key = mykey;
#pragma unroll
    for (int m = 32; m >= 1; m >>= 1) {
      unsigned long long o = shfl_xor_u64(key, m);
      key = (o > key) ? o : key;
    }
    if ((t & 63) == 0) wkey[s & 1][t >> 6] = key;
    __syncthreads();
    unsigned long long kb = wkey[s & 1][0];
#pragma unroll
    for (int w = 1; w < 8; w++) { unsigned long long o = wkey[s & 1][w]; kb = (o > kb) ? o : kb; }
    if (mykey == kb) {   // unique winner thread: publish coords + index
      c3[0] = bx; c3[1] = by; c3[2] = bz;
      sel[s] = (int)(0xFFFFFFFFu - (unsigned)kb);
    }
    __syncthreads();
  }
}

// ---------------- precompute U = x @ w1[:64,:] ------------------------------
__global__ __launch_bounds__(64) void xw1_kernel(const float* __restrict__ x,
                                                 const float* __restrict__ w1,
                                                 float* __restrict__ U) {
  __shared__ float xs[NIN];
  const int n = blockIdx.x, t = threadIdx.x;
  xs[t] = x[n * NIN + t];
  __syncthreads();
  for (int c = t; c < DIM; c += 64) {
    float acc = 0.0f;
#pragma unroll 8
    for (int r = 0; r < NIN; r++) acc = fmaf(xs[r], w1[r * DIM + c], acc);
    U[n * DIM + c] = acc;
  }
}

// ---------------- ball query: one WAVE per centroid -------------------------
#define CAP 2048
__global__ __launch_bounds__(64) void ballq_kernel(const float* __restrict__ pos,
                                                   const int* __restrict__ sel,
                                                   int* __restrict__ nbr,
                                                   int* __restrict__ nvalid) {
  __shared__ unsigned long long keys[CAP];
  __shared__ int cnt;
  const int i = blockIdx.x;
  const int lane = threadIdx.x;
  if (lane == 0) cnt = 0;
  __syncthreads();
  int ci = sel[i]; ci = min(max(ci, 0), N_PTS - 1);
  const float X = pos[3*ci], Y = pos[3*ci+1], Z = pos[3*ci+2];
  for (int k = 0; k < N_PTS / 64; k++) {
    int g = lane + 64 * k;
    float dx = __fsub_rn(pos[3*g+0], X);
    float dy = __fsub_rn(pos[3*g+1], Y);
    float dz = __fsub_rn(pos[3*g+2], Z);
    float q  = __fadd_rn(__fadd_rn(__fmul_rn(dx,dx), __fmul_rn(dy,dy)), __fmul_rn(dz,dz));
    if (q <= R2) {
      int p = atomicAdd(&cnt, 1);
      if (p < CAP)
        keys[p] = (((unsigned long long)__float_as_uint(q)) << 32) | (unsigned)g;
    }
  }
  __syncthreads();
  const int n = min(cnt, CAP);
  // 64 rounds: extract ascending (d2,idx) keys. Each lane only touches its own
  // strided slots (p ≡ lane mod 64), so no cross-lane LDS deps inside rounds.
  for (int r = 0; r < KNBR; r++) {
    unsigned long long mk = ~0ull; int mp = -1;
    for (int p = lane; p < n; p += 64) {
      unsigned long long kk = keys[p];
      if (kk < mk) { mk = kk; mp = p; }
    }
    unsigned long long rk = mk;
#pragma unroll
    for (int m = 32; m >= 1; m >>= 1) {
      unsigned long long o = shfl_xor_u64(rk, m);
      rk = (o < rk) ? o : rk;
    }
    if (rk != ~0ull && rk == mk && mp >= 0) keys[mp] = ~0ull;  // unique winner clears own slot
    if (lane == 0)
      nbr[i * KNBR + r] = (rk != ~0ull) ? (int)(unsigned)(rk & 0xFFFFFFFFull) : 0;
  }
  if (lane == 0) nvalid[i] = min(n, KNBR);
}

// ---------------- MLP (U-precomputed path): w2 column in registers ----------
__global__ __launch_bounds__(128) void mlp_u_kernel(
    const float* __restrict__ U, const float* __restrict__ pos,
    const float* __restrict__ w1, const float* __restrict__ b1,
    const float* __restrict__ g1, const float* __restrict__ be1,
    const float* __restrict__ w2, const float* __restrict__ b2,
    const float* __restrict__ g2, const float* __restrict__ be2,
    const int* __restrict__ sel, const int* __restrict__ nbr,
    const int* __restrict__ nvalid, float* __restrict__ out) {
  __shared__ float Us[KNBR * DIM];
  __shared__ float relx[KNBR], rely[KNBR], relz[KNBR];
  __shared__ float h1[DIM];
  __shared__ float w1r[3][DIM], b1s[DIM], g1s[DIM], be1s[DIM];
  __shared__ int nbrs_s[KNBR];
  const int i = blockIdx.x, t = threadIdx.x;
  int nv = nvalid[i]; nv = min(max(nv, 0), KNBR);
  float w2r[DIM];
#pragma unroll
  for (int c = 0; c < DIM; c++) w2r[c] = w2[c * NOUT + t];
  if (t < KNBR) {
    int nj = (t < nv) ? nbr[i * KNBR + t] : 0;
    nbrs_s[t] = min(max(nj, 0), N_PTS - 1);
  }
  if (t < DIM) {
    w1r[0][t] = w1[64*DIM + t]; w1r[1][t] = w1[65*DIM + t]; w1r[2][t] = w1[66*DIM + t];
    b1s[t] = b1[t]; g1s[t] = g1[t]; be1s[t] = be1[t];
  }
  __syncthreads();
  int ci = sel[i]; ci = min(max(ci, 0), N_PTS - 1);
  const float cx = pos[3*ci], cy = pos[3*ci+1], cz = pos[3*ci+2];
  if (t < KNBR && t < nv) {
    int nj = nbrs_s[t];
    relx[t] = pos[3*nj+0] - cx; rely[t] = pos[3*nj+1] - cy; relz[t] = pos[3*nj+2] - cz;
  }
  for (int e = t; e < nv * DIM; e += 128) {
    int r = e / DIM, c = e - r * DIM;
    Us[e] = U[nbrs_s[r] * DIM + c];
  }
  __syncthreads();
  const float b2d = b2[t], g2d = g2[t], be2d = be2[t];
  float omax = -3.4028235e38f;
  for (int j = 0; j < nv; j++) {
    if (t < DIM) {
      float z = Us[j*DIM + t];
      z = fmaf(relx[j], w1r[0][t], z);
      z = fmaf(rely[j], w1r[1][t], z);
      z = fmaf(relz[j], w1r[2][t], z);
      z += b1s[t];
      z = fmaxf(z, 0.0f);
      h1[t] = g1s[t] * (z * BNI) + be1s[t];
    }
    __syncthreads();
    float a0 = 0.f, a1 = 0.f, a2 = 0.f, a3 = 0.f;
#pragma unroll
    for (int c = 0; c < 64; c += 4) {
      a0 = fmaf(h1[c+0], w2r[c+0], a0);
      a1 = fmaf(h1[c+1], w2r[c+1], a1);
      a2 = fmaf(h1[c+2], w2r[c+2], a2);
      a3 = fmaf(h1[c+3], w2r[c+3], a3);
    }
    a0 = fmaf(h1[64], w2r[64], a0);
    a1 = fmaf(h1[65], w2r[65], a1);
    a2 = fmaf(h1[66], w2r[66], a2);
    float acc = ((a0 + a1) + (a2 + a3)) + b2d;
    float h2v = g2d * (fmaxf(acc, 0.0f) * BNI) + be2d;
    omax = fmaxf(omax, h2v);
    __syncthreads();
  }
  if (nv == 0) omax = 0.0f;
  out[i*NOUT + t] = omax;
}

// ---------------- MLP fallback (verified round-3 path, reads x directly) ----
__global__ __launch_bounds__(128) void mlp_direct_kernel(
    const float* __restrict__ x, const float* __restrict__ pos,
    const float* __restrict__ w1, const float* __restrict__ b1,
    const float* __restrict__ g1, const float* __restrict__ be1,
    const float* __restrict__ w2, const float* __restrict__ b2,
    const float* __restrict__ g2, const float* __restrict__ be2,
    const int* __restrict__ sel, const int* __restrict__ nbr,
    const int* __restrict__ nvalid, float* __restrict__ out) {
  __shared__ float xs[NIN];
  __shared__ float h1[DIM];
  __shared__ float rel[3];
  const int i = blockIdx.x, t = threadIdx.x;
  int ci = sel[i]; ci = min(max(ci, 0), N_PTS - 1);
  const float cx = pos[3*ci], cy = pos[3*ci+1], cz = pos[3*ci+2];
  int nv = nvalid[i]; nv = min(max(nv, 0), KNBR);
  float omax = -3.4028235e38f;
  for (int j = 0; j < nv; j++) {
    int nj = nbr[i*KNBR + j]; nj = min(max(nj, 0), N_PTS - 1);
    if (t < NIN) xs[t] = x[nj*NIN + t];
    if (t == 0) { rel[0] = pos[3*nj]-cx; rel[1] = pos[3*nj+1]-cy; rel[2] = pos[3*nj+2]-cz; }
    __syncthreads();
    if (t < DIM) {
      float z = b1[t];
      for (int r = 0; r < NIN; r++) z = fmaf(xs[r], w1[r*DIM + t], z);
      z = fmaf(rel[0], w1[64*DIM + t], z);
      z = fmaf(rel[1], w1[65*DIM + t], z);
      z = fmaf(rel[2], w1[66*DIM + t], z);
      z = fmaxf(z, 0.0f);
      h1[t] = g1[t] * (z * BNI) + be1[t];
    }
    __syncthreads();
    float acc = b2[t];
    for (int c = 0; c < DIM; c++) acc = fmaf(h1[c], w2[c*NOUT + t], acc);
    float h2v = g2[t] * (fmaxf(acc, 0.0f) * BNI) + be2[t];
    omax = fmaxf(omax, h2v);
    __syncthreads();
  }
  if (nv == 0) omax = 0.0f;
  out[i*NOUT + t] = omax;
}

// ---------------- finalize: pos_s, batch, idx (float32 out) -----------------
__global__ void fin_kernel(const float* __restrict__ pos, const int* __restrict__ batch,
                           const int* __restrict__ sel, float* __restrict__ out) {
  int i = blockIdx.x * blockDim.x + threadIdx.x;
  if (i < M_CTR) {
    int s = sel[i];
    int sc = min(max(s, 0), N_PTS - 1);
    out[M_CTR*NOUT + 3*i + 0] = pos[3*sc+0];
    out[M_CTR*NOUT + 3*i + 1] = pos[3*sc+1];
    out[M_CTR*NOUT + 3*i + 2] = pos[3*sc+2];
    out[M_CTR*NOUT + 3*M_CTR + i] = (float)batch[sc];
    out[M_CTR*NOUT + 4*M_CTR + i] = (float)s;
  }
}

extern "C" void kernel_launch(void* const* d_in, const int* in_sizes, int n_in,
                              void* d_out, int out_size, void* d_ws, size_t ws_size,
                              hipStream_t stream) {
  const float* x   = (const float*)d_in[0];
  const float* pos = (const float*)d_in[1];
  const int*  batch= (const int*)d_in[2];
  const float* w1  = (const float*)d_in[3];
  const float* b1  = (const float*)d_in[4];
  const float* g1  = (const float*)d_in[5];
  const float* be1 = (const float*)d_in[6];
  const float* w2  = (const float*)d_in[7];
  const float* b2  = (const float*)d_in[8];
  const float* g2  = (const float*)d_in[9];
  const float* be2 = (const float*)d_in[10];
  float* out = (float*)d_out;

  char*  ws   = (char*)d_ws;
  int*   sel  = (int*)(ws);
  int*   nvld = (int*)(ws + 16384);
  int*   nbr  = (int*)(ws + 32768);
  float* U    = (float*)(ws + 1081344);
  const bool useU = (ws_size >= (size_t)1081344 + (size_t)N_PTS * DIM * 4);

  hipLaunchKernelGGL(fps_kernel,   dim3(1),      dim3(FPS_T), 0, stream, pos, sel);
  hipLaunchKernelGGL(ballq_kernel, dim3(M_CTR),  dim3(64),    0, stream, pos, sel, nbr, nvld);
  if (useU) {
    hipLaunchKernelGGL(xw1_kernel, dim3(N_PTS),  dim3(64),    0, stream, x, w1, U);
    hipLaunchKernelGGL(mlp_u_kernel, dim3(M_CTR), dim3(128),  0, stream,
                       U, pos, w1, b1, g1, be1, w2, b2, g2, be2, sel, nbr, nvld, out);
  } else {
    hipLaunchKernelGGL(mlp_direct_kernel, dim3(M_CTR), dim3(128), 0, stream,
                       x, pos, w1, b1, g1, be1, w2, b2, g2, be2, sel, nbr, nvld, out);
  }
  hipLaunchKernelGGL(fin_kernel,   dim3(16),     dim3(256),   0, stream, pos, batch, sel, out);
}

// Round 6
// 7902.126 us; speedup vs baseline: 4.6052x; 1.0022x over previous
//
#include <hip/hip_runtime.h>
#include <hip/hip_bf16.h>

#define N_PTS 16384
#define M_CTR 4096
#define NIN   64
#define NOUT  128
#define DIM   67
#define KNBR  64
#define R2    0.25f
#define BNI   0.9999950000374997f   // 1/sqrt(1+1e-5)

// ws layout (bytes): sel int[4096] @0 ; nvalid int[4096] @16384 ; nbr int[4096*64] @32768 ;
//                    U float[16384*67] @1081344 (ends 5472256) — used only if ws_size permits

__device__ inline unsigned long long shfl_xor_u64(unsigned long long v, int m){
  int lo = __shfl_xor((int)(unsigned)v, m, 64);
  int hi = __shfl_xor((int)(unsigned)(v >> 32), m, 64);
  return ((unsigned long long)(unsigned)hi << 32) | (unsigned)lo;
}

// ---------------- FPS: single block, 1024 thr, exact numpy rounding ---------
#define FPS_T 1024
#define FPS_K (N_PTS / FPS_T)   // 16 points per thread, strided ownership
#define FPS_W (FPS_T / 64)      // 16 waves

__global__ __launch_bounds__(FPS_T) void fps_kernel(const float* __restrict__ pos,
                                                    int* __restrict__ sel) {
  __shared__ float c3[3];
  __shared__ unsigned long long wkey[FPS_W];
  const int t = threadIdx.x;
  float px[FPS_K], py[FPS_K], pz[FPS_K], dmin[FPS_K];
#pragma unroll
  for (int k = 0; k < FPS_K; k++) {
    int g = t + FPS_T * k;
    px[k] = pos[3*g+0]; py[k] = pos[3*g+1]; pz[k] = pos[3*g+2];
    dmin[k] = 3.4028235e38f;
  }
  if (t == 0) { c3[0] = pos[0]; c3[1] = pos[1]; c3[2] = pos[2]; sel[0] = 0; }
  __syncthreads();
  for (int s = 1; s < M_CTR; s++) {
    const float X = c3[0], Y = c3[1], Z = c3[2];   // read before barrier1
    float v = 0.0f;
    int iL = 0;
#pragma unroll
    for (int k = 0; k < FPS_K; k++) {
      // exact (p-c)^2, no fma contraction, (xx+yy)+zz order — matches np
      float dx = __fsub_rn(px[k], X);
      float dy = __fsub_rn(py[k], Y);
      float dz = __fsub_rn(pz[k], Z);
      float q  = __fadd_rn(__fadd_rn(__fmul_rn(dx,dx), __fmul_rn(dy,dy)), __fmul_rn(dz,dz));
      float d  = fminf(dmin[k], q);
      dmin[k]  = d;
      bool c = d > v;            // strict > keeps earliest k (lowest g) on ties
      v  = c ? d : v;
      iL = c ? k : iL;
    }
    unsigned g = (unsigned)t + ((unsigned)iL * FPS_T);
    unsigned long long key =
        (((unsigned long long)__float_as_uint(v)) << 32) |
        (unsigned long long)(0xFFFFFFFFu - g);   // larger val wins; ties -> smaller idx
#pragma unroll
    for (int m = 32; m >= 1; m >>= 1) {
      unsigned long long o = shfl_xor_u64(key, m);
      key = (o > key) ? o : key;
    }
    if ((t & 63) == 0) wkey[t >> 6] = key;
    __syncthreads();                              // barrier 1: wkey visible
    if (t < 64) {                                 // wave 0 finishes the reduce
      unsigned long long kk = (t < FPS_W) ? wkey[t] : 0ull;
#pragma unroll
      for (int m = 8; m >= 1; m >>= 1) {
        unsigned long long o = shfl_xor_u64(kk, m);
        kk = (o > kk) ? o : kk;
      }
      if (t == 0) {
        unsigned gw = 0xFFFFFFFFu - (unsigned)(kk & 0xFFFFFFFFull);
        c3[0] = pos[3*gw+0]; c3[1] = pos[3*gw+1]; c3[2] = pos[3*gw+2];
        sel[s] = (int)gw;
      }
    }
    __syncthreads();                              // barrier 2: c3 ready
  }
}

// ---------------- precompute U = x @ w1[:64,:] ------------------------------
__global__ __launch_bounds__(64) void xw1_kernel(const float* __restrict__ x,
                                                 const float* __restrict__ w1,
                                                 float* __restrict__ U) {
  __shared__ float xs[NIN];
  const int n = blockIdx.x, t = threadIdx.x;
  xs[t] = x[n * NIN + t];
  __syncthreads();
  for (int c = t; c < DIM; c += 64) {
    float acc = 0.0f;
#pragma unroll 8
    for (int r = 0; r < NIN; r++) acc = fmaf(xs[r], w1[r * DIM + c], acc);
    U[n * DIM + c] = acc;
  }
}

// ---------------- ball query: one WAVE per centroid -------------------------
#define CAP 2048
__global__ __launch_bounds__(64) void ballq_kernel(const float* __restrict__ pos,
                                                   const int* __restrict__ sel,
                                                   int* __restrict__ nbr,
                                                   int* __restrict__ nvalid) {
  __shared__ unsigned long long keys[CAP];
  __shared__ int cnt;
  const int i = blockIdx.x;
  const int lane = threadIdx.x;
  if (lane == 0) cnt = 0;
  __syncthreads();
  int ci = sel[i]; ci = min(max(ci, 0), N_PTS - 1);
  const float X = pos[3*ci], Y = pos[3*ci+1], Z = pos[3*ci+2];
  for (int k = 0; k < N_PTS / 64; k++) {
    int g = lane + 64 * k;
    float dx = __fsub_rn(pos[3*g+0], X);
    float dy = __fsub_rn(pos[3*g+1], Y);
    float dz = __fsub_rn(pos[3*g+2], Z);
    float q  = __fadd_rn(__fadd_rn(__fmul_rn(dx,dx), __fmul_rn(dy,dy)), __fmul_rn(dz,dz));
    if (q <= R2) {
      int p = atomicAdd(&cnt, 1);
      if (p < CAP)
        keys[p] = (((unsigned long long)__float_as_uint(q)) << 32) | (unsigned)g;
    }
  }
  __syncthreads();
  const int n = min(cnt, CAP);
  for (int r = 0; r < KNBR; r++) {
    unsigned long long mk = ~0ull; int mp = -1;
    for (int p = lane; p < n; p += 64) {
      unsigned long long kk = keys[p];
      if (kk < mk) { mk = kk; mp = p; }
    }
    unsigned long long rk = mk;
#pragma unroll
    for (int m = 32; m >= 1; m >>= 1) {
      unsigned long long o = shfl_xor_u64(rk, m);
      rk = (o < rk) ? o : rk;
    }
    if (rk != ~0ull && rk == mk && mp >= 0) keys[mp] = ~0ull;  // unique winner clears own slot
    if (lane == 0)
      nbr[i * KNBR + r] = (rk != ~0ull) ? (int)(unsigned)(rk & 0xFFFFFFFFull) : 0;
  }
  if (lane == 0) nvalid[i] = min(n, KNBR);
}

// ---------------- MLP (U-precomputed path): w2 column in registers ----------
__global__ __launch_bounds__(128) void mlp_u_kernel(
    const float* __restrict__ U, const float* __restrict__ pos,
    const float* __restrict__ w1, const float* __restrict__ b1,
    const float* __restrict__ g1, const float* __restrict__ be1,
    const float* __restrict__ w2, const float* __restrict__ b2,
    const float* __restrict__ g2, const float* __restrict__ be2,
    const int* __restrict__ sel, const int* __restrict__ nbr,
    const int* __restrict__ nvalid, float* __restrict__ out) {
  __shared__ float Us[KNBR * DIM];
  __shared__ float relx[KNBR], rely[KNBR], relz[KNBR];
  __shared__ float h1[DIM];
  __shared__ float w1r[3][DIM], b1s[DIM], g1s[DIM], be1s[DIM];
  __shared__ int nbrs_s[KNBR];
  const int i = blockIdx.x, t = threadIdx.x;
  int nv = nvalid[i]; nv = min(max(nv, 0), KNBR);
  float w2r[DIM];
#pragma unroll
  for (int c = 0; c < DIM; c++) w2r[c] = w2[c * NOUT + t];
  if (t < KNBR) {
    int nj = (t < nv) ? nbr[i * KNBR + t] : 0;
    nbrs_s[t] = min(max(nj, 0), N_PTS - 1);
  }
  if (t < DIM) {
    w1r[0][t] = w1[64*DIM + t]; w1r[1][t] = w1[65*DIM + t]; w1r[2][t] = w1[66*DIM + t];
    b1s[t] = b1[t]; g1s[t] = g1[t]; be1s[t] = be1[t];
  }
  __syncthreads();
  int ci = sel[i]; ci = min(max(ci, 0), N_PTS - 1);
  const float cx = pos[3*ci], cy = pos[3*ci+1], cz = pos[3*ci+2];
  if (t < KNBR && t < nv) {
    int nj = nbrs_s[t];
    relx[t] = pos[3*nj+0] - cx; rely[t] = pos[3*nj+1] - cy; relz[t] = pos[3*nj+2] - cz;
  }
  for (int e = t; e < nv * DIM; e += 128) {
    int r = e / DIM, c = e - r * DIM;
    Us[e] = U[nbrs_s[r] * DIM + c];
  }
  __syncthreads();
  const float b2d = b2[t], g2d = g2[t], be2d = be2[t];
  float omax = -3.4028235e38f;
  for (int j = 0; j < nv; j++) {
    if (t < DIM) {
      float z = Us[j*DIM + t];
      z = fmaf(relx[j], w1r[0][t], z);
      z = fmaf(rely[j], w1r[1][t], z);
      z = fmaf(relz[j], w1r[2][t], z);
      z += b1s[t];
      z = fmaxf(z, 0.0f);
      h1[t] = g1s[t] * (z * BNI) + be1s[t];
    }
    __syncthreads();
    float a0 = 0.f, a1 = 0.f, a2 = 0.f, a3 = 0.f;
#pragma unroll
    for (int c = 0; c < 64; c += 4) {
      a0 = fmaf(h1[c+0], w2r[c+0], a0);
      a1 = fmaf(h1[c+1], w2r[c+1], a1);
      a2 = fmaf(h1[c+2], w2r[c+2], a2);
      a3 = fmaf(h1[c+3], w2r[c+3], a3);
    }
    a0 = fmaf(h1[64], w2r[64], a0);
    a1 = fmaf(h1[65], w2r[65], a1);
    a2 = fmaf(h1[66], w2r[66], a2);
    float acc = ((a0 + a1) + (a2 + a3)) + b2d;
    float h2v = g2d * (fmaxf(acc, 0.0f) * BNI) + be2d;
    omax = fmaxf(omax, h2v);
    __syncthreads();
  }
  if (nv == 0) omax = 0.0f;
  out[i*NOUT + t] = omax;
}

// ---------------- MLP fallback (reads x directly) ---------------------------
__global__ __launch_bounds__(128) void mlp_direct_kernel(
    const float* __restrict__ x, const float* __restrict__ pos,
    const float* __restrict__ w1, const float* __restrict__ b1,
    const float* __restrict__ g1, const float* __restrict__ be1,
    const float* __restrict__ w2, const float* __restrict__ b2,
    const float* __restrict__ g2, const float* __restrict__ be2,
    const int* __restrict__ sel, const int* __restrict__ nbr,
    const int* __restrict__ nvalid, float* __restrict__ out) {
  __shared__ float xs[NIN];
  __shared__ float h1[DIM];
  __shared__ float rel[3];
  const int i = blockIdx.x, t = threadIdx.x;
  int ci = sel[i]; ci = min(max(ci, 0), N_PTS - 1);
  const float cx = pos[3*ci], cy = pos[3*ci+1], cz = pos[3*ci+2];
  int nv = nvalid[i]; nv = min(max(nv, 0), KNBR);
  float omax = -3.4028235e38f;
  for (int j = 0; j < nv; j++) {
    int nj = nbr[i*KNBR + j]; nj = min(max(nj, 0), N_PTS - 1);
    if (t < NIN) xs[t] = x[nj*NIN + t];
    if (t == 0) { rel[0] = pos[3*nj]-cx; rel[1] = pos[3*nj+1]-cy; rel[2] = pos[3*nj+2]-cz; }
    __syncthreads();
    if (t < DIM) {
      float z = b1[t];
      for (int r = 0; r < NIN; r++) z = fmaf(xs[r], w1[r*DIM + t], z);
      z = fmaf(rel[0], w1[64*DIM + t], z);
      z = fmaf(rel[1], w1[65*DIM + t], z);
      z = fmaf(rel[2], w1[66*DIM + t], z);
      z = fmaxf(z, 0.0f);
      h1[t] = g1[t] * (z * BNI) + be1[t];
    }
    __syncthreads();
    float acc = b2[t];
    for (int c = 0; c < DIM; c++) acc = fmaf(h1[c], w2[c*NOUT + t], acc);
    float h2v = g2[t] * (fmaxf(acc, 0.0f) * BNI) + be2[t];
    omax = fmaxf(omax, h2v);
    __syncthreads();
  }
  if (nv == 0) omax = 0.0f;
  out[i*NOUT + t] = omax;
}

// ---------------- finalize: pos_s, batch, idx (float32 out) -----------------
__global__ void fin_kernel(const float* __restrict__ pos, const int* __restrict__ batch,
                           const int* __restrict__ sel, float* __restrict__ out) {
  int i = blockIdx.x * blockDim.x + threadIdx.x;
  if (i < M_CTR) {
    int s = sel[i];
    int sc = min(max(s, 0), N_PTS - 1);
    out[M_CTR*NOUT + 3*i + 0] = pos[3*sc+0];
    out[M_CTR*NOUT + 3*i + 1] = pos[3*sc+1];
    out[M_CTR*NOUT + 3*i + 2] = pos[3*sc+2];
    out[M_CTR*NOUT + 3*M_CTR + i] = (float)batch[sc];
    out[M_CTR*NOUT + 4*M_CTR + i] = (float)s;
  }
}

extern "C" void kernel_launch(void* const* d_in, const int* in_sizes, int n_in,
                              void* d_out, int out_size, void* d_ws, size_t ws_size,
                              hipStream_t stream) {
  const float* x   = (const float*)d_in[0];
  const float* pos = (const float*)d_in[1];
  const int*  batch= (const int*)d_in[2];
  const float* w1  = (const float*)d_in[3];
  const float* b1  = (const float*)d_in[4];
  const float* g1  = (const float*)d_in[5];
  const float* be1 = (const float*)d_in[6];
  const float* w2  = (const float*)d_in[7];
  const float* b2  = (const float*)d_in[8];
  const float* g2  = (const float*)d_in[9];
  const float* be2 = (const float*)d_in[10];
  float* out = (float*)d_out;

  char*  ws   = (char*)d_ws;
  int*   sel  = (int*)(ws);
  int*   nvld = (int*)(ws + 16384);
  int*   nbr  = (int*)(ws + 32768);
  float* U    = (float*)(ws + 1081344);
  const bool useU = (ws_size >= (size_t)1081344 + (size_t)N_PTS * DIM * 4);

  hipLaunchKernelGGL(fps_kernel,   dim3(1),      dim3(FPS_T), 0, stream, pos, sel);
  hipLaunchKernelGGL(ballq_kernel, dim3(M_CTR),  dim3(64),    0, stream, pos, sel, nbr, nvld);
  if (useU) {
    hipLaunchKernelGGL(xw1_kernel, dim3(N_PTS),  dim3(64),    0, stream, x, w1, U);
    hipLaunchKernelGGL(mlp_u_kernel, dim3(M_CTR), dim3(128),  0, stream,
                       U, pos, w1, b1, g1, be1, w2, b2, g2, be2, sel, nbr, nvld, out);
  } else {
    hipLaunchKernelGGL(mlp_direct_kernel, dim3(M_CTR), dim3(128), 0, stream,
                       x, pos, w1, b1, g1, be1, w2, b2, g2, be2, sel, nbr, nvld, out);
  }
  hipLaunchKernelGGL(fin_kernel,   dim3(16),     dim3(256),   0, stream, pos, batch, sel, out);
}

// Round 7
// 7531.720 us; speedup vs baseline: 4.8317x; 1.0492x over previous
//
#include <hip/hip_runtime.h>
#include <hip/hip_bf16.h>

#define N_PTS 16384
#define M_CTR 4096
#define NIN   64
#define NOUT  128
#define DIM   67
#define KNBR  64
#define R2    0.25f
#define BNI   0.9999950000374997f   // 1/sqrt(1+1e-5)

// ws layout (bytes): sel int[4096] @0 ; nvalid int[4096] @16384 ; nbr int[4096*64] @32768 ;
//                    U float[16384*67] @1081344 (ends 5472256) — used only if ws_size permits

__device__ inline unsigned long long shfl_xor_u64(unsigned long long v, int m){
  int lo = __shfl_xor((int)(unsigned)v, m, 64);
  int hi = __shfl_xor((int)(unsigned)(v >> 32), m, 64);
  return ((unsigned long long)(unsigned)hi << 32) | (unsigned)lo;
}

// ---------------- FPS: single block, 1024 thr, ONE barrier per round --------
#define FPS_T 1024
#define FPS_K (N_PTS / FPS_T)   // 16 points per thread, strided ownership
#define FPS_W (FPS_T / 64)      // 16 waves

__global__ __launch_bounds__(FPS_T) void fps_kernel(const float* __restrict__ pos,
                                                    int* __restrict__ sel) {
  __shared__ unsigned long long wkey[2][FPS_W];   // parity double-buffer
  const int t = threadIdx.x;
  float px[FPS_K], py[FPS_K], pz[FPS_K], dmin[FPS_K];
#pragma unroll
  for (int k = 0; k < FPS_K; k++) {
    int g = t + FPS_T * k;
    px[k] = pos[3*g+0]; py[k] = pos[3*g+1]; pz[k] = pos[3*g+2];
    dmin[k] = 3.4028235e38f;
  }
  if (t == 0) sel[0] = 0;
  // all threads hold current centroid coords in registers (broadcast loads)
  float X = pos[0], Y = pos[1], Z = pos[2];
  for (int s = 1; s < M_CTR; s++) {
    float v = 0.0f;
    int iL = 0;
#pragma unroll
    for (int k = 0; k < FPS_K; k++) {
      // exact (p-c)^2, no fma contraction, (xx+yy)+zz order — matches np
      float dx = __fsub_rn(px[k], X);
      float dy = __fsub_rn(py[k], Y);
      float dz = __fsub_rn(pz[k], Z);
      float q  = __fadd_rn(__fadd_rn(__fmul_rn(dx,dx), __fmul_rn(dy,dy)), __fmul_rn(dz,dz));
      float d  = fminf(dmin[k], q);
      dmin[k]  = d;
      bool c = d > v;            // strict > keeps earliest k (lowest g) on ties
      v  = c ? d : v;
      iL = c ? k : iL;
    }
    unsigned g = (unsigned)t + ((unsigned)iL * FPS_T);
    unsigned long long key =
        (((unsigned long long)__float_as_uint(v)) << 32) |
        (unsigned long long)(0xFFFFFFFFu - g);   // larger val wins; ties -> smaller idx
#pragma unroll
    for (int m = 32; m >= 1; m >>= 1) {
      unsigned long long o = shfl_xor_u64(key, m);
      key = (o > key) ? o : key;
    }
    if ((t & 63) == 0) wkey[s & 1][t >> 6] = key;
    __syncthreads();                              // the ONLY barrier this round
    // every thread redundantly reduces the 16 wave keys (LDS broadcast reads)
    unsigned long long kb = wkey[s & 1][0];
#pragma unroll
    for (int w = 1; w < FPS_W; w++) {
      unsigned long long o = wkey[s & 1][w];
      kb = (o > kb) ? o : kb;
    }
    unsigned gw = 0xFFFFFFFFu - (unsigned)(kb & 0xFFFFFFFFull);
    if (t == 0) sel[s] = (int)gw;
    // same-address global load: one L1-hit fetch, broadcast to all lanes
    X = pos[3*gw+0]; Y = pos[3*gw+1]; Z = pos[3*gw+2];
  }
}

// ---------------- precompute U = x @ w1[:64,:] ------------------------------
__global__ __launch_bounds__(64) void xw1_kernel(const float* __restrict__ x,
                                                 const float* __restrict__ w1,
                                                 float* __restrict__ U) {
  __shared__ float xs[NIN];
  const int n = blockIdx.x, t = threadIdx.x;
  xs[t] = x[n * NIN + t];
  __syncthreads();
  for (int c = t; c < DIM; c += 64) {
    float acc = 0.0f;
#pragma unroll 8
    for (int r = 0; r < NIN; r++) acc = fmaf(xs[r], w1[r * DIM + c], acc);
    U[n * DIM + c] = acc;
  }
}

// ---------------- ball query: one WAVE per centroid -------------------------
#define CAP 2048
__global__ __launch_bounds__(64) void ballq_kernel(const float* __restrict__ pos,
                                                   const int* __restrict__ sel,
                                                   int* __restrict__ nbr,
                                                   int* __restrict__ nvalid) {
  __shared__ unsigned long long keys[CAP];
  __shared__ int cnt;
  const int i = blockIdx.x;
  const int lane = threadIdx.x;
  if (lane == 0) cnt = 0;
  __syncthreads();
  int ci = sel[i]; ci = min(max(ci, 0), N_PTS - 1);
  const float X = pos[3*ci], Y = pos[3*ci+1], Z = pos[3*ci+2];
  for (int k = 0; k < N_PTS / 64; k++) {
    int g = lane + 64 * k;
    float dx = __fsub_rn(pos[3*g+0], X);
    float dy = __fsub_rn(pos[3*g+1], Y);
    float dz = __fsub_rn(pos[3*g+2], Z);
    float q  = __fadd_rn(__fadd_rn(__fmul_rn(dx,dx), __fmul_rn(dy,dy)), __fmul_rn(dz,dz));
    if (q <= R2) {
      int p = atomicAdd(&cnt, 1);
      if (p < CAP)
        keys[p] = (((unsigned long long)__float_as_uint(q)) << 32) | (unsigned)g;
    }
  }
  __syncthreads();
  const int n = min(cnt, CAP);
  for (int r = 0; r < KNBR; r++) {
    unsigned long long mk = ~0ull; int mp = -1;
    for (int p = lane; p < n; p += 64) {
      unsigned long long kk = keys[p];
      if (kk < mk) { mk = kk; mp = p; }
    }
    unsigned long long rk = mk;
#pragma unroll
    for (int m = 32; m >= 1; m >>= 1) {
      unsigned long long o = shfl_xor_u64(rk, m);
      rk = (o < rk) ? o : rk;
    }
    if (rk != ~0ull && rk == mk && mp >= 0) keys[mp] = ~0ull;  // unique winner clears own slot
    if (lane == 0)
      nbr[i * KNBR + r] = (rk != ~0ull) ? (int)(unsigned)(rk & 0xFFFFFFFFull) : 0;
  }
  if (lane == 0) nvalid[i] = min(n, KNBR);
}

// ---------------- MLP (U-precomputed path): w2 column in registers ----------
__global__ __launch_bounds__(128) void mlp_u_kernel(
    const float* __restrict__ U, const float* __restrict__ pos,
    const float* __restrict__ w1, const float* __restrict__ b1,
    const float* __restrict__ g1, const float* __restrict__ be1,
    const float* __restrict__ w2, const float* __restrict__ b2,
    const float* __restrict__ g2, const float* __restrict__ be2,
    const int* __restrict__ sel, const int* __restrict__ nbr,
    const int* __restrict__ nvalid, float* __restrict__ out) {
  __shared__ float Us[KNBR * DIM];
  __shared__ float relx[KNBR], rely[KNBR], relz[KNBR];
  __shared__ float h1[DIM];
  __shared__ float w1r[3][DIM], b1s[DIM], g1s[DIM], be1s[DIM];
  __shared__ int nbrs_s[KNBR];
  const int i = blockIdx.x, t = threadIdx.x;
  int nv = nvalid[i]; nv = min(max(nv, 0), KNBR);
  float w2r[DIM];
#pragma unroll
  for (int c = 0; c < DIM; c++) w2r[c] = w2[c * NOUT + t];
  if (t < KNBR) {
    int nj = (t < nv) ? nbr[i * KNBR + t] : 0;
    nbrs_s[t] = min(max(nj, 0), N_PTS - 1);
  }
  if (t < DIM) {
    w1r[0][t] = w1[64*DIM + t]; w1r[1][t] = w1[65*DIM + t]; w1r[2][t] = w1[66*DIM + t];
    b1s[t] = b1[t]; g1s[t] = g1[t]; be1s[t] = be1[t];
  }
  __syncthreads();
  int ci = sel[i]; ci = min(max(ci, 0), N_PTS - 1);
  const float cx = pos[3*ci], cy = pos[3*ci+1], cz = pos[3*ci+2];
  if (t < KNBR && t < nv) {
    int nj = nbrs_s[t];
    relx[t] = pos[3*nj+0] - cx; rely[t] = pos[3*nj+1] - cy; relz[t] = pos[3*nj+2] - cz;
  }
  for (int e = t; e < nv * DIM; e += 128) {
    int r = e / DIM, c = e - r * DIM;
    Us[e] = U[nbrs_s[r] * DIM + c];
  }
  __syncthreads();
  const float b2d = b2[t], g2d = g2[t], be2d = be2[t];
  float omax = -3.4028235e38f;
  for (int j = 0; j < nv; j++) {
    if (t < DIM) {
      float z = Us[j*DIM + t];
      z = fmaf(relx[j], w1r[0][t], z);
      z = fmaf(rely[j], w1r[1][t], z);
      z = fmaf(relz[j], w1r[2][t], z);
      z += b1s[t];
      z = fmaxf(z, 0.0f);
      h1[t] = g1s[t] * (z * BNI) + be1s[t];
    }
    __syncthreads();
    float a0 = 0.f, a1 = 0.f, a2 = 0.f, a3 = 0.f;
#pragma unroll
    for (int c = 0; c < 64; c += 4) {
      a0 = fmaf(h1[c+0], w2r[c+0], a0);
      a1 = fmaf(h1[c+1], w2r[c+1], a1);
      a2 = fmaf(h1[c+2], w2r[c+2], a2);
      a3 = fmaf(h1[c+3], w2r[c+3], a3);
    }
    a0 = fmaf(h1[64], w2r[64], a0);
    a1 = fmaf(h1[65], w2r[65], a1);
    a2 = fmaf(h1[66], w2r[66], a2);
    float acc = ((a0 + a1) + (a2 + a3)) + b2d;
    float h2v = g2d * (fmaxf(acc, 0.0f) * BNI) + be2d;
    omax = fmaxf(omax, h2v);
    __syncthreads();
  }
  if (nv == 0) omax = 0.0f;
  out[i*NOUT + t] = omax;
}

// ---------------- MLP fallback (reads x directly) ---------------------------
__global__ __launch_bounds__(128) void mlp_direct_kernel(
    const float* __restrict__ x, const float* __restrict__ pos,
    const float* __restrict__ w1, const float* __restrict__ b1,
    const float* __restrict__ g1, const float* __restrict__ be1,
    const float* __restrict__ w2, const float* __restrict__ b2,
    const float* __restrict__ g2, const float* __restrict__ be2,
    const int* __restrict__ sel, const int* __restrict__ nbr,
    const int* __restrict__ nvalid, float* __restrict__ out) {
  __shared__ float xs[NIN];
  __shared__ float h1[DIM];
  __shared__ float rel[3];
  const int i = blockIdx.x, t = threadIdx.x;
  int ci = sel[i]; ci = min(max(ci, 0), N_PTS - 1);
  const float cx = pos[3*ci], cy = pos[3*ci+1], cz = pos[3*ci+2];
  int nv = nvalid[i]; nv = min(max(nv, 0), KNBR);
  float omax = -3.4028235e38f;
  for (int j = 0; j < nv; j++) {
    int nj = nbr[i*KNBR + j]; nj = min(max(nj, 0), N_PTS - 1);
    if (t < NIN) xs[t] = x[nj*NIN + t];
    if (t == 0) { rel[0] = pos[3*nj]-cx; rel[1] = pos[3*nj+1]-cy; rel[2] = pos[3*nj+2]-cz; }
    __syncthreads();
    if (t < DIM) {
      float z = b1[t];
      for (int r = 0; r < NIN; r++) z = fmaf(xs[r], w1[r*DIM + t], z);
      z = fmaf(rel[0], w1[64*DIM + t], z);
      z = fmaf(rel[1], w1[65*DIM + t], z);
      z = fmaf(rel[2], w1[66*DIM + t], z);
      z = fmaxf(z, 0.0f);
      h1[t] = g1[t] * (z * BNI) + be1[t];
    }
    __syncthreads();
    float acc = b2[t];
    for (int c = 0; c < DIM; c++) acc = fmaf(h1[c], w2[c*NOUT + t], acc);
    float h2v = g2[t] * (fmaxf(acc, 0.0f) * BNI) + be2[t];
    omax = fmaxf(omax, h2v);
    __syncthreads();
  }
  if (nv == 0) omax = 0.0f;
  out[i*NOUT + t] = omax;
}

// ---------------- finalize: pos_s, batch, idx (float32 out) -----------------
__global__ void fin_kernel(const float* __restrict__ pos, const int* __restrict__ batch,
                           const int* __restrict__ sel, float* __restrict__ out) {
  int i = blockIdx.x * blockDim.x + threadIdx.x;
  if (i < M_CTR) {
    int s = sel[i];
    int sc = min(max(s, 0), N_PTS - 1);
    out[M_CTR*NOUT + 3*i + 0] = pos[3*sc+0];
    out[M_CTR*NOUT + 3*i + 1] = pos[3*sc+1];
    out[M_CTR*NOUT + 3*i + 2] = pos[3*sc+2];
    out[M_CTR*NOUT + 3*M_CTR + i] = (float)batch[sc];
    out[M_CTR*NOUT + 4*M_CTR + i] = (float)s;
  }
}

extern "C" void kernel_launch(void* const* d_in, const int* in_sizes, int n_in,
                              void* d_out, int out_size, void* d_ws, size_t ws_size,
                              hipStream_t stream) {
  const float* x   = (const float*)d_in[0];
  const float* pos = (const float*)d_in[1];
  const int*  batch= (const int*)d_in[2];
  const float* w1  = (const float*)d_in[3];
  const float* b1  = (const float*)d_in[4];
  const float* g1  = (const float*)d_in[5];
  const float* be1 = (const float*)d_in[6];
  const float* w2  = (const float*)d_in[7];
  const float* b2  = (const float*)d_in[8];
  const float* g2  = (const float*)d_in[9];
  const float* be2 = (const float*)d_in[10];
  float* out = (float*)d_out;

  char*  ws   = (char*)d_ws;
  int*   sel  = (int*)(ws);
  int*   nvld = (int*)(ws + 16384);
  int*   nbr  = (int*)(ws + 32768);
  float* U    = (float*)(ws + 1081344);
  const bool useU = (ws_size >= (size_t)1081344 + (size_t)N_PTS * DIM * 4);

  hipLaunchKernelGGL(fps_kernel,   dim3(1),      dim3(FPS_T), 0, stream, pos, sel);
  hipLaunchKernelGGL(ballq_kernel, dim3(M_CTR),  dim3(64),    0, stream, pos, sel, nbr, nvld);
  if (useU) {
    hipLaunchKernelGGL(xw1_kernel, dim3(N_PTS),  dim3(64),    0, stream, x, w1, U);
    hipLaunchKernelGGL(mlp_u_kernel, dim3(M_CTR), dim3(128),  0, stream,
                       U, pos, w1, b1, g1, be1, w2, b2, g2, be2, sel, nbr, nvld, out);
  } else {
    hipLaunchKernelGGL(mlp_direct_kernel, dim3(M_CTR), dim3(128), 0, stream,
                       x, pos, w1, b1, g1, be1, w2, b2, g2, be2, sel, nbr, nvld, out);
  }
  hipLaunchKernelGGL(fin_kernel,   dim3(16),     dim3(256),   0, stream, pos, batch, sel, out);
}